// Round 2
// baseline (326.647 us; speedup 1.0000x reference)
//
#include <hip/hip_runtime.h>

// SNN forward — R6: barrier-free, LDS-free, ILP-driven.
//
// R5 post-mortem: VALU issue time identical to R4 (~26us) while wall time
// rose 80->89us with both pipes <30% and occupancy 61%. Diagnosis: the
// load->LDS->barrier->compute->LDS->barrier->flush chain convoys all waves;
// occupancy does not fix it (61% was slower than 40%). R6 removes every
// barrier and all LDS from the hot path:
//
//  - lane owns 4 consecutive rows: x = 80B contiguous, 16B-aligned
//    -> 5 independent global_load_dwordx4 (deep MLP per lane).
//    out = 160B contiguous -> 10 nontemporal dwordx4 stores.
//  - prep kernel (1 block) hoists per-block work into d_ws:
//      ws[0..159]  = W1^T as [5][32] (neuron pairs adjacent -> v_pk_fma_f32)
//      ws[160..191]= smx[i] = max_j W2[j][i]
//      ws[192]     = mxmax = max_i smx[i]
//  - gates (exact, verified margin analysis from R5, absmax 0.0):
//      gate1: popc(m)*mxmax < 1.998 -> no L2 spike possible (kills 99.3%)
//      gate2: S = sum_{i in m} smx[i] < 1.998 (via __shfl from lanes 0..31,
//             no LDS) -> kills ~90% of the rest
//    fp safety: sum error <= 31*2^-24*Sum|terms| ~ 4e-5 << 2e-3 margin.
//  - dense fallback (0.07% rows): VERBATIM R4/R5-verified ascending
//    set-bit order -> bit-identical.
//
// Layer-1 as v2f (ext_vector) math: clang emits llvm.fmuladd for the
// vector mul+add chain exactly as for the scalar chain that verified
// absmax=0.0; v_pk_fma_f32 is two IEEE fmas -> bit-exact, half the issue.

typedef float v4f __attribute__((ext_vector_type(4)));
typedef float v2f __attribute__((ext_vector_type(2)));

#define TPB 256
#define RPL 4                 // rows per lane
#define RPB (TPB * RPL)       // 1024 rows per block

// ---- prep: runs once per graph replay, 1 block ----
__global__ __launch_bounds__(64) void snn_prep(
    const float* __restrict__ W1,   // [32,5]
    const float* __restrict__ W2,   // [32,32]
    float* __restrict__ ws)
{
    const int t = threadIdx.x;      // 0..63
    float mm = -3.4e38f;
    if (t < 32) {
#pragma unroll
        for (int k = 0; k < 5; ++k) ws[k * 32 + t] = W1[t * 5 + k];
        mm = W2[t];
#pragma unroll
        for (int j = 1; j < 32; ++j) mm = fmaxf(mm, W2[j * 32 + t]);
        ws[160 + t] = mm;
    }
#pragma unroll
    for (int off = 32; off; off >>= 1) mm = fmaxf(mm, __shfl_xor(mm, off));
    if (t == 0) ws[192] = mm;
}

__global__ __launch_bounds__(TPB) void snn_fused(
    const float* __restrict__ x,
    const float* __restrict__ W2,   // [32,32]
    const float* __restrict__ W3,   // [16,32]
    const float* __restrict__ W4,   // [10,16]
    const float* __restrict__ ws,
    float* __restrict__ out,        // [B,10]
    int B)
{
    const long gtid = (long)blockIdx.x * TPB + threadIdx.x;
    const long r0 = gtid * RPL;
    if (r0 >= B) return;
    const bool full = (r0 + RPL <= B);

    const v2f* __restrict__ w1p = (const v2f*)ws;          // [5][16] pairs
    const float smxv = ws[160 + (threadIdx.x & 31)];       // lane<32 holds smx[lane]
    const float mxmax = ws[192];                           // uniform s_load

    // ---- x: 20 floats, 80B contiguous, 16B aligned ----
    __align__(16) float xf[RPL * 5];
    if (full) {
        const v4f* xg = (const v4f*)(x + r0 * 5);
        v4f* xv = (v4f*)xf;
#pragma unroll
        for (int e = 0; e < 5; ++e) xv[e] = xg[e];
    } else {
#pragma unroll
        for (int e = 0; e < RPL * 5; ++e) xf[e] = 0.0f;
        for (int c = 0; c < RPL; ++c)
            if (r0 + c < B)
#pragma unroll
                for (int k = 0; k < 5; ++k) xf[c * 5 + k] = x[(r0 + c) * 5 + k];
    }

    __align__(16) float o[RPL * 10];
#pragma unroll
    for (int e = 0; e < RPL * 10; ++e) o[e] = 0.0f;

    // ---- per-row compute, no cross-lane deps except rare gate2/dense ----
#pragma unroll
    for (int c = 0; c < RPL; ++c) {
        const float x0 = xf[c * 5 + 0], x1 = xf[c * 5 + 1], x2 = xf[c * 5 + 2];
        const float x3 = xf[c * 5 + 3], x4 = xf[c * 5 + 4];

        // layer 1, packed pairs; per-neuron chain = mul, then 4 adds in
        // k-order == verified scalar order (each half independent)
        v2f hp[16];
#pragma unroll
        for (int j2 = 0; j2 < 16; ++j2) hp[j2] = x0 * w1p[j2];
#pragma unroll
        for (int j2 = 0; j2 < 16; ++j2) hp[j2] += x1 * w1p[16 + j2];
#pragma unroll
        for (int j2 = 0; j2 < 16; ++j2) hp[j2] += x2 * w1p[32 + j2];
#pragma unroll
        for (int j2 = 0; j2 < 16; ++j2) hp[j2] += x3 * w1p[48 + j2];
#pragma unroll
        for (int j2 = 0; j2 < 16; ++j2) hp[j2] += x4 * w1p[64 + j2];

        unsigned m = 0u;
#pragma unroll
        for (int j2 = 0; j2 < 16; ++j2) {
            if (hp[j2].x >= 2.0f) m |= (1u << (2 * j2));
            if (hp[j2].y >= 2.0f) m |= (1u << (2 * j2 + 1));
        }

        // gate 1 (per-lane, 3 ops)
        const bool need = m && ((float)__popc(m) * mxmax >= 1.998f);
        if (__any(need)) {
            // gate 2: S = sum smx[i] over set bits, via bpermute (no LDS)
            float S = 0.0f;
            unsigned mm = need ? m : 0u;
            while (__any(mm)) {
                const int i = mm ? (__ffs(mm) - 1) : 0;
                const float v = __shfl(smxv, i);
                if (mm) { S += v; mm &= mm - 1; }
            }
            if (need && S >= 1.998f) {
                // rare dense path: VERBATIM R4/R5-verified, ascending
                // set-bit order == reference order
                float h2[32];
#pragma unroll
                for (int j = 0; j < 32; ++j) h2[j] = 0.0f;
                mm = m;
                while (mm) {
                    const int i = __ffs(mm) - 1;
                    mm &= mm - 1;
                    const float* col = W2 + i;   // W2^T[i][j] == W2[j*32+i]
#pragma unroll
                    for (int j = 0; j < 32; ++j) h2[j] += col[j * 32];
                }
                unsigned m2 = 0u;
#pragma unroll
                for (int j = 0; j < 32; ++j)
                    if (h2[j] >= 2.0f) m2 |= (1u << j);

                if (m2) {  // ultra-rare: exact layers 3+4
                    unsigned m3 = 0u;
#pragma unroll
                    for (int j = 0; j < 16; ++j) {
                        float g = 0.0f;
#pragma unroll
                        for (int i = 0; i < 32; ++i)
                            if ((m2 >> i) & 1u) g += W3[j * 32 + i];
                        if (g >= 2.0f) m3 |= (1u << j);
                    }
#pragma unroll
                    for (int j = 0; j < 10; ++j) {
                        float g = 0.0f;
#pragma unroll
                        for (int i = 0; i < 16; ++i)
                            if ((m3 >> i) & 1u) g += W4[j * 16 + i];
                        o[c * 10 + j] = (g >= 2.0f) ? 1.0f : 0.0f;
                    }
                }
            }
        }
    }

    // ---- out: 40 floats, 160B contiguous, 16B aligned ----
    if (full) {
        v4f* og = (v4f*)(out + r0 * 10);
        const v4f* o4 = (const v4f*)o;
#pragma unroll
        for (int e = 0; e < 10; ++e) __builtin_nontemporal_store(o4[e], &og[e]);
    } else {
        for (int c = 0; c < RPL; ++c)
            if (r0 + c < B)
#pragma unroll
                for (int j = 0; j < 10; ++j) out[(r0 + c) * 10 + j] = o[c * 10 + j];
    }
}

extern "C" void kernel_launch(void* const* d_in, const int* in_sizes, int n_in,
                              void* d_out, int out_size, void* d_ws, size_t ws_size,
                              hipStream_t stream) {
    const float* x  = (const float*)d_in[0];
    const float* W1 = (const float*)d_in[1];
    const float* W2 = (const float*)d_in[2];
    const float* W3 = (const float*)d_in[3];
    const float* W4 = (const float*)d_in[4];
    float* out = (float*)d_out;
    float* ws  = (float*)d_ws;

    int B = in_sizes[0] / 5;
    snn_prep<<<1, 64, 0, stream>>>(W1, W2, ws);
    int grid = (B + RPB - 1) / RPB;
    snn_fused<<<grid, TPB, 0, stream>>>(x, W2, W3, W4, ws, out, B);
}

// Round 3
// 157.977 us; speedup vs baseline: 2.0677x; 2.0677x over previous
//
#include <hip/hip_runtime.h>

// SNN forward — R7: coalesced IO + barrier-free via WAVE-LOCAL LDS staging.
//
// Lessons: R4/R5 (block barriers, coalesced) = 80-89us; R6 (no barriers,
// per-lane-contiguous IO) = 265us from 4.6x write amplification (16B
// nontemporal partial writes -> 64B HBM txns). R7 combines: coalesced
// 1KB/instr global IO (like R4) with zero block-wide barriers (like R6).
// Each wave stages ONLY its own 256 rows through its private 10KB LDS
// region; intra-wave LDS ordering needs only lgkmcnt (compiler-inserted),
// no s_barrier. W1 reload amortized 4x via j2-outer/rows-inner loop
// (R4/R5 paid ~160 uniform loads PER ROW, comparable to the FMA count).
//
// Exactness (absmax 0.0 preserved):
//  - packed v2f layer-1: per-neuron chain mul,+,+,+,+ in k-order, each
//    pair half an independent chain == R6-verified code (which passed).
//    Reordering independent neurons/rows has no fp effect.
//  - gates: popc(m)*mxmax < 1.998 and S=sum smx[i] < 1.998 provably imply
//    reference h2[j] < 2.0 (fp sum err <= 31*2^-24*Sum|terms| ~ 4e-5).
//  - dense fallback: VERBATIM R4/R5/R6-verified ascending set-bit order.
//
// LDS bank audit: x readback lane*80B stride-20 -> 2-way (free);
// zero-fill & flush e*64+lane -> 2-way (free); rare dense writes 4-way.

typedef float v4f __attribute__((ext_vector_type(4)));
typedef float v2f __attribute__((ext_vector_type(2)));

#define TPB 256
#define RPL 4                  // rows per lane
#define WROWS (64 * RPL)       // 256 rows per wave
#define RPB (TPB * RPL)        // 1024 rows per block

// ---- prep (1 block, once per replay): verified in R6 ----
// ws[0..159]  = W1^T as [5][32] floats (pairs adjacent -> v2f loads)
// ws[160..191]= smx[i] = max_j W2[j][i];  ws[192] = mxmax
__global__ __launch_bounds__(64) void snn_prep(
    const float* __restrict__ W1,   // [32,5]
    const float* __restrict__ W2,   // [32,32]
    float* __restrict__ ws)
{
    const int t = threadIdx.x;      // 0..63
    float mm = -3.4e38f;
    if (t < 32) {
#pragma unroll
        for (int k = 0; k < 5; ++k) ws[k * 32 + t] = W1[t * 5 + k];
        mm = W2[t];
#pragma unroll
        for (int j = 1; j < 32; ++j) mm = fmaxf(mm, W2[j * 32 + t]);
        ws[160 + t] = mm;
    }
#pragma unroll
    for (int off = 32; off; off >>= 1) mm = fmaxf(mm, __shfl_xor(mm, off));
    if (t == 0) ws[192] = mm;
}

__global__ __launch_bounds__(TPB) void snn_fused(
    const float* __restrict__ x,
    const float* __restrict__ W2,   // [32,32]
    const float* __restrict__ W3,   // [16,32]
    const float* __restrict__ W4,   // [10,16]
    const float* __restrict__ ws,
    float* __restrict__ out,        // [B,10]
    int B)
{
    __shared__ __align__(16) float stage[4][WROWS * 10];   // 40KB, per-wave 10KB

    const int t = threadIdx.x;
    const int wv = t >> 6, lane = t & 63;
    float* sbuf = stage[wv];
    const long wrow0 = (long)blockIdx.x * RPB + (long)wv * WROWS;
    if (wrow0 >= B) return;

    const v2f* __restrict__ w1p = (const v2f*)ws;   // [5][16] neuron-pairs
    const float* __restrict__ smx = ws + 160;
    const float mxmax = ws[192];

    if (wrow0 + WROWS <= B) {
        // ---- coalesced x stage: 1280 floats = 320 v4f, 5/lane, intra-wave ----
        const v4f* xg = (const v4f*)(x + wrow0 * 5);
        v4f* s4 = (v4f*)sbuf;
#pragma unroll
        for (int e = 0; e < 5; ++e) s4[e * 64 + lane] = xg[e * 64 + lane];

        // own 20 x floats back (lane*80B, 2-way banked = free)
        v4f xq[5];
        {
            const v4f* sx = (const v4f*)(sbuf + lane * 20);
#pragma unroll
            for (int e = 0; e < 5; ++e) xq[e] = sx[e];
        }
        const float* xf = (const float*)xq;

        // ---- coalesced zero-fill of out region (x regs are live now) ----
        {
            v4f z = {0.0f, 0.0f, 0.0f, 0.0f};
#pragma unroll
            for (int e = 0; e < 10; ++e) s4[e * 64 + lane] = z;
        }

        // ---- layer 1: j2-outer (weights amortized over 4 rows) ----
        unsigned m[RPL] = {0u, 0u, 0u, 0u};
#pragma unroll
        for (int j2 = 0; j2 < 16; ++j2) {
            const v2f wa = w1p[j2], wb = w1p[16 + j2], wc = w1p[32 + j2];
            const v2f wd = w1p[48 + j2], we = w1p[64 + j2];
#pragma unroll
            for (int c = 0; c < RPL; ++c) {
                v2f h = xf[c * 5 + 0] * wa;   // exact per-neuron chain order
                h += xf[c * 5 + 1] * wb;
                h += xf[c * 5 + 2] * wc;
                h += xf[c * 5 + 3] * wd;
                h += xf[c * 5 + 4] * we;
                if (h.x >= 2.0f) m[c] |= (1u << (2 * j2));
                if (h.y >= 2.0f) m[c] |= (1u << (2 * j2 + 1));
            }
        }

        // ---- gates + rare dense path ----
#pragma unroll
        for (int c = 0; c < RPL; ++c) {
            const unsigned mc = m[c];
            if (mc && ((float)__popc(mc) * mxmax >= 1.998f)) {
                float S = 0.0f;
                unsigned mm = mc;
                while (mm) { int i = __ffs(mm) - 1; mm &= mm - 1; S += smx[i]; }
                if (S >= 1.998f) {
                    // dense path: VERBATIM verified, ascending set-bit order
                    float h2[32];
#pragma unroll
                    for (int j = 0; j < 32; ++j) h2[j] = 0.0f;
                    mm = mc;
                    while (mm) {
                        const int i = __ffs(mm) - 1;
                        mm &= mm - 1;
                        const float* col = W2 + i;   // W2^T[i][j] == W2[j*32+i]
#pragma unroll
                        for (int j = 0; j < 32; ++j) h2[j] += col[j * 32];
                    }
                    unsigned m2 = 0u;
#pragma unroll
                    for (int j = 0; j < 32; ++j)
                        if (h2[j] >= 2.0f) m2 |= (1u << j);

                    if (m2) {   // ultra-rare: exact layers 3+4, write LDS
                        unsigned m3 = 0u;
#pragma unroll
                        for (int j = 0; j < 16; ++j) {
                            float g = 0.0f;
#pragma unroll
                            for (int i = 0; i < 32; ++i)
                                if ((m2 >> i) & 1u) g += W3[j * 32 + i];
                            if (g >= 2.0f) m3 |= (1u << j);
                        }
                        float* orow = sbuf + (lane * RPL + c) * 10;
#pragma unroll
                        for (int j = 0; j < 10; ++j) {
                            float g = 0.0f;
#pragma unroll
                            for (int i = 0; i < 16; ++i)
                                if ((m3 >> i) & 1u) g += W4[j * 16 + i];
                            orow[j] = (g >= 2.0f) ? 1.0f : 0.0f;
                        }
                    }
                }
            }
        }

        // ---- coalesced nontemporal flush: 2560 floats = 640 v4f, 10/lane ----
        v4f* og = (v4f*)(out + wrow0 * 10);
        const v4f* s4c = (const v4f*)sbuf;
#pragma unroll
        for (int e = 0; e < 10; ++e)
            __builtin_nontemporal_store(s4c[e * 64 + lane], &og[e * 64 + lane]);
    } else {
        // ---- tail (never hit at B=2^21; correctness-general) ----
        for (int c = 0; c < RPL; ++c) {
            const long r = wrow0 + (long)lane * RPL + c;
            if (r >= B) continue;
            float xr[5];
#pragma unroll
            for (int k = 0; k < 5; ++k) xr[k] = x[r * 5 + k];
            unsigned mc = 0u;
#pragma unroll
            for (int j2 = 0; j2 < 16; ++j2) {
                v2f h = xr[0] * w1p[j2];
                h += xr[1] * w1p[16 + j2];
                h += xr[2] * w1p[32 + j2];
                h += xr[3] * w1p[48 + j2];
                h += xr[4] * w1p[64 + j2];
                if (h.x >= 2.0f) mc |= (1u << (2 * j2));
                if (h.y >= 2.0f) mc |= (1u << (2 * j2 + 1));
            }
            float o[10];
#pragma unroll
            for (int j = 0; j < 10; ++j) o[j] = 0.0f;
            if (mc && ((float)__popc(mc) * mxmax >= 1.998f)) {
                float S = 0.0f;
                unsigned mm = mc;
                while (mm) { int i = __ffs(mm) - 1; mm &= mm - 1; S += smx[i]; }
                if (S >= 1.998f) {
                    float h2[32];
#pragma unroll
                    for (int j = 0; j < 32; ++j) h2[j] = 0.0f;
                    mm = mc;
                    while (mm) {
                        const int i = __ffs(mm) - 1;
                        mm &= mm - 1;
                        const float* col = W2 + i;
#pragma unroll
                        for (int j = 0; j < 32; ++j) h2[j] += col[j * 32];
                    }
                    unsigned m2 = 0u;
#pragma unroll
                    for (int j = 0; j < 32; ++j)
                        if (h2[j] >= 2.0f) m2 |= (1u << j);
                    if (m2) {
                        unsigned m3 = 0u;
#pragma unroll
                        for (int j = 0; j < 16; ++j) {
                            float g = 0.0f;
#pragma unroll
                            for (int i = 0; i < 32; ++i)
                                if ((m2 >> i) & 1u) g += W3[j * 32 + i];
                            if (g >= 2.0f) m3 |= (1u << j);
                        }
#pragma unroll
                        for (int j = 0; j < 10; ++j) {
                            float g = 0.0f;
#pragma unroll
                            for (int i = 0; i < 16; ++i)
                                if ((m3 >> i) & 1u) g += W4[j * 16 + i];
                            o[j] = (g >= 2.0f) ? 1.0f : 0.0f;
                        }
                    }
                }
            }
#pragma unroll
            for (int j = 0; j < 10; ++j) out[r * 10 + j] = o[j];
        }
    }
}

extern "C" void kernel_launch(void* const* d_in, const int* in_sizes, int n_in,
                              void* d_out, int out_size, void* d_ws, size_t ws_size,
                              hipStream_t stream) {
    const float* x  = (const float*)d_in[0];
    const float* W1 = (const float*)d_in[1];
    const float* W2 = (const float*)d_in[2];
    const float* W3 = (const float*)d_in[3];
    const float* W4 = (const float*)d_in[4];
    float* out = (float*)d_out;
    float* ws  = (float*)d_ws;

    int B = in_sizes[0] / 5;
    snn_prep<<<1, 64, 0, stream>>>(W1, W2, ws);
    int grid = (B + RPB - 1) / RPB;
    snn_fused<<<grid, TPB, 0, stream>>>(x, W2, W3, W4, ws, out, B);
}